// Round 13
// baseline (479.812 us; speedup 1.0000x reference)
//
#include <hip/hip_runtime.h>
#include <hip/hip_bf16.h>

#define HIDDEN 2048
#define INNER  1024
#define NE     64
#define TOPK   8
#define NTOK   512

typedef float f32x4 __attribute__((ext_vector_type(4)));
typedef short bf16x8 __attribute__((ext_vector_type(8)));

static __device__ __forceinline__ unsigned short b16(float f) {
  return __builtin_bit_cast(unsigned short, __float2bfloat16(f));
}
static __device__ __forceinline__ unsigned int pk2(float lo, float hi) {
  return (unsigned)b16(lo) | ((unsigned)b16(hi) << 16);
}

// XCD-affinity decode for grid 2048: expert e -> XCD e&7.
static __device__ __forceinline__ void decode_ce32(int flat, int& c, int& e) {
  int xcd = flat & 7, s = flat >> 3;
  c = s & 31;
  e = ((s >> 5) << 3) | xcd;
}

// ---- gating: xconv + out-zero + gate dot + topk; last block does scan+scatter ----
__global__ __launch_bounds__(256) void gating_kernel(
    const float* __restrict__ x, const float* __restrict__ gw, const float* __restrict__ gb,
    int* __restrict__ ticket, int* __restrict__ counts, int* __restrict__ offsets,
    int* __restrict__ topk_e, float* __restrict__ topk_w,
    int* __restrict__ perm_tok, float* __restrict__ perm_wt,
    unsigned short* __restrict__ xb, float* __restrict__ out) {
  const int t = blockIdx.x;
  const int tid = threadIdx.x;
  const int lane = tid & 63, w = tid >> 6;

  {
    const float4* xi = (const float4*)(x + (size_t)t * HIDDEN);
    float4 v0 = xi[tid * 2], v1 = xi[tid * 2 + 1];
    ushort4 o0, o1;
    o0.x = b16(v0.x); o0.y = b16(v0.y); o0.z = b16(v0.z); o0.w = b16(v0.w);
    o1.x = b16(v1.x); o1.y = b16(v1.y); o1.z = b16(v1.z); o1.w = b16(v1.w);
    ushort4* xo = (ushort4*)(xb + (size_t)t * HIDDEN);
    xo[tid * 2] = o0; xo[tid * 2 + 1] = o1;
    f32x4 z = (f32x4)0.f;
    f32x4* orow = (f32x4*)(out + (size_t)t * HIDDEN);
    orow[tid * 2] = z; orow[tid * 2 + 1] = z;
  }

  const int e = tid >> 2, seg = tid & 3;
  const f32x4* gr = (const f32x4*)(gw + (size_t)e * HIDDEN);
  const f32x4* xr = (const f32x4*)(x + (size_t)t * HIDDEN);
  float acc = 0.f;
  #pragma unroll 8
  for (int k = 0; k < 128; ++k) {
    int idx = k * 4 + seg;
    f32x4 a = xr[idx], b = gr[idx];
    acc += a.x * b.x + a.y * b.y + a.z * b.z + a.w * b.w;
  }
  acc += __shfl_xor(acc, 1);
  acc += __shfl_xor(acc, 2);
  __shared__ float sP[NE];
  if (seg == 0) sP[e] = acc;
  __syncthreads();

  __shared__ float sW[TOPK];
  __shared__ int   sE[TOPK];
  if (w == 0) {
    float logit = gb[lane] + sP[lane];
    float m = logit;
    #pragma unroll
    for (int off = 32; off; off >>= 1) m = fmaxf(m, __shfl_xor(m, off));
    float p = __expf(logit - m);
    float s = p;
    #pragma unroll
    for (int off = 32; off; off >>= 1) s += __shfl_xor(s, off);
    p /= s;
    float myp = p;
    #pragma unroll
    for (int k = 0; k < TOPK; ++k) {
      float v = myp; int ei = lane;
      #pragma unroll
      for (int off = 32; off; off >>= 1) {
        float v2 = __shfl_xor(v, off); int e2 = __shfl_xor(ei, off);
        if (v2 > v || (v2 == v && e2 < ei)) { v = v2; ei = e2; }
      }
      if (lane == 0) { sW[k] = v; sE[k] = ei; }
      if (lane == ei) myp = -1.0f;
    }
  }
  __syncthreads();
  if (tid < TOPK) {
    float ss = 0.f;
    #pragma unroll
    for (int k = 0; k < TOPK; ++k) ss += sW[k];
    topk_e[t * TOPK + tid] = sE[tid];
    topk_w[t * TOPK + tid] = sW[tid] / ss;
  }

  __threadfence();
  __syncthreads();
  __shared__ int slast;
  if (tid == 0) {
    int old = atomicAdd(ticket, 1);
    slast = (old == (int)gridDim.x - 1);
  }
  __syncthreads();
  if (!slast) return;
  __threadfence();

  __shared__ int hcnt[NE], soff[NE], ccur[NE];
  if (tid < NE) hcnt[tid] = 0;
  __syncthreads();
  for (int i = tid; i < NTOK * TOPK; i += 256) atomicAdd(&hcnt[topk_e[i]], 1);
  __syncthreads();
  if (tid < NE) {
    int c = hcnt[tid];
    int s = c;
    #pragma unroll
    for (int off = 1; off < 64; off <<= 1) {
      int o = __shfl_up(s, off);
      if (tid >= off) s += o;
    }
    soff[tid] = s - c; ccur[tid] = 0;
    counts[tid] = c; offsets[tid] = s - c;
  }
  __syncthreads();
  for (int i = tid; i < NTOK * TOPK; i += 256) {
    int ee = topk_e[i];
    int p = atomicAdd(&ccur[ee], 1);
    int pos = soff[ee] + p;
    perm_tok[pos] = i >> 3;
    perm_wt[pos] = topk_w[i];
  }
}

// ---- phase 1: act = gelu(x@w1g^T) * (x@w1u^T) ----
// 256 threads, tile 128M x 32N(gate)+32N(up), BK=32, dbuf LDS 32KB -> 4 blocks/CU
__global__ __launch_bounds__(256, 4) void phase1_kernel(
    const unsigned short* __restrict__ xb, const float* __restrict__ w1,
    const int* __restrict__ offsets, const int* __restrict__ counts,
    const int* __restrict__ perm_tok, unsigned short* __restrict__ act) {
  int c, e;
  decode_ce32(blockIdx.x, c, e);
  const int n_e = counts[e];
  if (n_e == 0) return;
  const int off = offsets[e];
  const int tid = threadIdx.x;
  const int lane = tid & 63, wave = tid >> 6;
  const int u2 = lane >> 4, l15 = lane & 15;
  const int mat = wave >> 1;          // 0=gate, 1=up
  const int wm  = (wave & 1) * 64;

  // B staging: 64 rows (32 gate + 32 up), 4 threads/row, 32B (8 floats) each
  const int brow = tid >> 2, bseg = tid & 3;
  const float* wg = w1 + (size_t)e * (2 * INNER) * HIDDEN;
  const float* brp = (brow < 32)
      ? wg + (size_t)(c * 32 + brow) * HIDDEN
      : wg + (size_t)(INNER + c * 32 + (brow - 32)) * HIDDEN;
  const int bslot = bseg ^ (brow & 3);

  // A staging: 128 rows, 2 threads/row, 32B (2 uint4) each
  const int arow = tid >> 1, ah = tid & 1;
  const int aslot0 = (ah * 2) ^ (arow & 3);
  const int aslot1 = (ah * 2 + 1) ^ (arow & 3);

  // smem[buf]: A = [0,512) uint4 (8KB, 128 rows x 4 slots), B = [512,768) (4KB... 64 rows x 4 slots = 256)
  __shared__ uint4 smem[2][768];
  __shared__ int stok[128];
  float (*sU)[36] = (float(*)[36])&smem[0][0];   // 18.4KB, epilogue only (spans both bufs)

  for (int m0 = 0; m0 < n_e; m0 += 128) {
    __syncthreads();
    if (tid < 128) {
      int idx = m0 + tid;
      stok[tid] = perm_tok[off + (idx < n_e ? idx : n_e - 1)];
    }
    __syncthreads();

    const unsigned short* xrow = xb + (size_t)stok[arow] * HIDDEN;

    uint4 va0 = ((const uint4*)xrow)[ah * 2];
    uint4 va1 = ((const uint4*)xrow)[ah * 2 + 1];
    f32x4 vB0 = ((const f32x4*)brp)[bseg * 2];
    f32x4 vB1 = ((const f32x4*)brp)[bseg * 2 + 1];

    f32x4 acc[4][2];
    #pragma unroll
    for (int i = 0; i < 4; ++i)
      #pragma unroll
      for (int j = 0; j < 2; ++j) acc[i][j] = (f32x4)0.f;

    for (int k0 = 0; k0 < HIDDEN; k0 += 32) {
      const int cur = (k0 >> 5) & 1;
      uint4* A = smem[cur];
      uint4* B = smem[cur] + 512;
      A[arow * 4 + aslot0] = va0;
      A[arow * 4 + aslot1] = va1;
      B[brow * 4 + bslot] = (uint4){ pk2(vB0.x, vB0.y), pk2(vB0.z, vB0.w),
                                     pk2(vB1.x, vB1.y), pk2(vB1.z, vB1.w) };
      __syncthreads();
      int k1 = k0 + 32;
      if (k1 < HIDDEN) {
        va0 = ((const uint4*)(xrow + k1))[ah * 2];
        va1 = ((const uint4*)(xrow + k1))[ah * 2 + 1];
        vB0 = ((const f32x4*)(brp + k1))[bseg * 2];
        vB1 = ((const f32x4*)(brp + k1))[bseg * 2 + 1];
      }
      bf16x8 af[4], bfr[2];
      #pragma unroll
      for (int mi = 0; mi < 4; ++mi) {
        int r = wm + mi * 16 + l15;
        af[mi] = __builtin_bit_cast(bf16x8, A[r * 4 + (u2 ^ (r & 3))]);
      }
      #pragma unroll
      for (int ni = 0; ni < 2; ++ni) {
        int r = mat * 32 + ni * 16 + l15;
        bfr[ni] = __builtin_bit_cast(bf16x8, B[r * 4 + (u2 ^ (r & 3))]);
      }
      #pragma unroll
      for (int mi = 0; mi < 4; ++mi)
        #pragma unroll
        for (int ni = 0; ni < 2; ++ni)
          acc[mi][ni] = __builtin_amdgcn_mfma_f32_16x16x32_bf16(af[mi], bfr[ni], acc[mi][ni], 0, 0, 0);
    }

    __syncthreads();
    if (mat == 1) {
      #pragma unroll
      for (int mi = 0; mi < 4; ++mi)
        #pragma unroll
        for (int ni = 0; ni < 2; ++ni)
          #pragma unroll
          for (int r4 = 0; r4 < 4; ++r4)
            sU[wm + mi * 16 + u2 * 4 + r4][ni * 16 + l15] = acc[mi][ni][r4];
    }
    __syncthreads();
    if (mat == 0) {
      #pragma unroll
      for (int mi = 0; mi < 4; ++mi)
        #pragma unroll
        for (int r4 = 0; r4 < 4; ++r4) {
          int mrow = wm + mi * 16 + u2 * 4 + r4;
          int m = m0 + mrow;
          if (m < n_e) {
            unsigned short* arw = act + (size_t)(off + m) * INNER + c * 32;
            #pragma unroll
            for (int ni = 0; ni < 2; ++ni) {
              int col = ni * 16 + l15;
              float g = acc[mi][ni][r4];
              float uu = sU[mrow][col];
              float ge = g / (1.0f + __expf(-1.5957691216057308f * (g + 0.044715f * g * g * g)));
              arw[col] = b16(ge * uu);
            }
          }
        }
    }
  }
}

// ---- phase 2: out[tok] += wt * (act @ w2[e]^T), atomic epilogue ----
// 256 threads, tile 128M x 64N, BK=32, dbuf LDS 24KB -> 4 blocks/CU
__global__ __launch_bounds__(256, 4) void phase2_kernel(
    const unsigned short* __restrict__ act, const float* __restrict__ w2,
    const int* __restrict__ offsets, const int* __restrict__ counts,
    const int* __restrict__ perm_tok, const float* __restrict__ perm_wt,
    float* __restrict__ out) {
  int c, e;
  decode_ce32(blockIdx.x, c, e);
  const int n_e = counts[e];
  if (n_e == 0) return;
  const int off = offsets[e];
  const int tid = threadIdx.x;
  const int lane = tid & 63, wave = tid >> 6;
  const int u2 = lane >> 4, l15 = lane & 15;
  const int wm = wave * 32;

  // B staging: 64 w2 rows, 4 threads/row, 32B each
  const int brow = tid >> 2, bseg = tid & 3;
  const float* brp = w2 + ((size_t)e * HIDDEN + c * 64 + brow) * INNER;
  const int bslot = bseg ^ (brow & 3);

  // A staging: 128 act rows, 2 threads/row, 32B each
  const int arow = tid >> 1, ah = tid & 1;
  const int aslot0 = (ah * 2) ^ (arow & 3);
  const int aslot1 = (ah * 2 + 1) ^ (arow & 3);

  __shared__ uint4 smem[2][768];
  __shared__ int   stok[128];
  __shared__ float swt[128];

  for (int m0 = 0; m0 < n_e; m0 += 128) {
    __syncthreads();
    if (tid < 128) {
      int idx = m0 + tid;
      int cl = idx < n_e ? idx : n_e - 1;
      stok[tid] = perm_tok[off + cl];
      swt[tid] = (idx < n_e) ? perm_wt[off + cl] : 0.f;
    }
    __syncthreads();

    const unsigned short* arp = act + (size_t)(off + (m0 + arow < n_e ? m0 + arow : n_e - 1)) * INNER;

    uint4 va0 = ((const uint4*)arp)[ah * 2];
    uint4 va1 = ((const uint4*)arp)[ah * 2 + 1];
    f32x4 vB0 = ((const f32x4*)brp)[bseg * 2];
    f32x4 vB1 = ((const f32x4*)brp)[bseg * 2 + 1];

    f32x4 acc[2][4];
    #pragma unroll
    for (int i = 0; i < 2; ++i)
      #pragma unroll
      for (int j = 0; j < 4; ++j) acc[i][j] = (f32x4)0.f;

    for (int k0 = 0; k0 < INNER; k0 += 32) {
      const int cur = (k0 >> 5) & 1;
      uint4* A = smem[cur];
      uint4* B = smem[cur] + 512;
      A[arow * 4 + aslot0] = va0;
      A[arow * 4 + aslot1] = va1;
      B[brow * 4 + bslot] = (uint4){ pk2(vB0.x, vB0.y), pk2(vB0.z, vB0.w),
                                     pk2(vB1.x, vB1.y), pk2(vB1.z, vB1.w) };
      __syncthreads();
      int k1 = k0 + 32;
      if (k1 < INNER) {
        va0 = ((const uint4*)(arp + k1))[ah * 2];
        va1 = ((const uint4*)(arp + k1))[ah * 2 + 1];
        vB0 = ((const f32x4*)(brp + k1))[bseg * 2];
        vB1 = ((const f32x4*)(brp + k1))[bseg * 2 + 1];
      }
      bf16x8 af[2], bfr[4];
      #pragma unroll
      for (int mi = 0; mi < 2; ++mi) {
        int r = wm + mi * 16 + l15;
        af[mi] = __builtin_bit_cast(bf16x8, A[r * 4 + (u2 ^ (r & 3))]);
      }
      #pragma unroll
      for (int ni = 0; ni < 4; ++ni) {
        int r = ni * 16 + l15;
        bfr[ni] = __builtin_bit_cast(bf16x8, B[r * 4 + (u2 ^ (r & 3))]);
      }
      #pragma unroll
      for (int mi = 0; mi < 2; ++mi)
        #pragma unroll
        for (int ni = 0; ni < 4; ++ni)
          acc[mi][ni] = __builtin_amdgcn_mfma_f32_16x16x32_bf16(af[mi], bfr[ni], acc[mi][ni], 0, 0, 0);
    }

    #pragma unroll
    for (int mi = 0; mi < 2; ++mi)
      #pragma unroll
      for (int r4 = 0; r4 < 4; ++r4) {
        int mrow = wm + mi * 16 + u2 * 4 + r4;
        int m = m0 + mrow;
        if (m < n_e) {
          int tok = stok[mrow];
          float wt = swt[mrow];
          float* orow = out + (size_t)tok * HIDDEN + c * 64;
          #pragma unroll
          for (int ni = 0; ni < 4; ++ni)
            atomicAdd(&orow[ni * 16 + l15], wt * acc[mi][ni][r4]);
        }
      }
    __syncthreads();
  }
}

extern "C" void kernel_launch(void* const* d_in, const int* in_sizes, int n_in,
                              void* d_out, int out_size, void* d_ws, size_t ws_size,
                              hipStream_t stream) {
  const float* x  = (const float*)d_in[0];
  const float* gw = (const float*)d_in[1];
  const float* gb = (const float*)d_in[2];
  const float* w1 = (const float*)d_in[3];
  const float* w2 = (const float*)d_in[4];
  float* out = (float*)d_out;

  char* ws = (char*)d_ws;
  int*   ticket   = (int*)(ws + 0x000);
  int*   counts   = (int*)(ws + 0x100);
  int*   offsets  = (int*)(ws + 0x200);
  int*   topk_e   = (int*)(ws + 0x1000);
  float* topk_w   = (float*)(ws + 0x5000);
  int*   perm_tok = (int*)(ws + 0x9000);
  float* perm_wt  = (float*)(ws + 0xD000);
  unsigned short* xb  = (unsigned short*)(ws + 0x11000);    // 2 MB
  unsigned short* act = (unsigned short*)(ws + 0x220000);   // 8 MB

  hipMemsetAsync(ticket, 0, 0x40, stream);

  gating_kernel<<<NTOK, 256, 0, stream>>>(x, gw, gb, ticket, counts, offsets,
                                          topk_e, topk_w, perm_tok, perm_wt, xb, out);
  phase1_kernel<<<2048, 256, 0, stream>>>(xb, w1, offsets, counts, perm_tok, act);
  phase2_kernel<<<2048, 256, 0, stream>>>(act, w2, offsets, counts, perm_tok, perm_wt, out);
}